// Round 2
// baseline (252.204 us; speedup 1.0000x reference)
//
#include <hip/hip_runtime.h>
#include <hip/hip_bf16.h>

// Problem constants (from reference)
#define BB 4
#define CC 64
#define NXX 432
#define NYY 496
#define GG (NXX * NYY)          // 214272 cells per batch
#define PP 80000                // total pillars (B * P_PER)

typedef float v4f __attribute__((ext_vector_type(4)));

// Reference reduces to a dense BEV scatter: prob_buf is zeros (kept bug) so
// p == 0 -> out = spatial. Output [B,C,NY,NX] = pillar_features scattered.

// Workspace layout: [0, B*G) int cell->pillar map, then 64 floats of zeros
// (a "zero pillar row" that empty cells gather from -- removes all per-element
// cndmask selects in the hot kernel).
#define ZROW_INT_OFF (BB * GG)

// Kernel 1: init cell->pillar map to -1, and zero the zero-row.
__global__ void k_init_map(int* __restrict__ map) {
    int i = blockIdx.x * blockDim.x + threadIdx.x;   // one int4 per thread
    const int n4 = (BB * GG) / 4;                    // 214272
    if (i < n4) {
        ((int4*)map)[i] = make_int4(-1, -1, -1, -1);
    }
    if (i < 16) {                                    // 64 floats = 16 int4
        ((int4*)(map + ZROW_INT_OFF))[i] = make_int4(0, 0, 0, 0);
    }
}

// Kernel 2: scatter pillar ids into the map (coords unique per batch).
__global__ void k_scatter_ids(const int* __restrict__ coords, int* __restrict__ map) {
    int i = blockIdx.x * blockDim.x + threadIdx.x;
    if (i < PP) {
        int4 cd = ((const int4*)coords)[i];          // (b, z, y, x), z == 0
        int g = cd.x * GG + cd.y + cd.z * NXX + cd.w;
        map[g] = i;
    }
}

// Kernel 3: gather. Thread = 4 consecutive cells x ALL 64 channels.
// vs r0/r1: (1) NORMAL stores (not nontemporal) -- the 877MB harness fill
// proves normal L2-combined stores reach 6.5 TB/s; nt was the one untested
// lever on the store path. (2) Single channel slice: map read once (3.4 MB,
// was 13.7-27 MB) and each occupied pf row read as 4 full contiguous 64B
// lines (slicing split rows below line size -> read amplification).
// Occupancy is proven irrelevant (r1: 2x waves, neutral), so consolidating
// work per thread costs nothing on the latency side.
__global__ void __launch_bounds__(256, 4) k_gather(const float* __restrict__ pf,
                                                   const int* __restrict__ map,
                                                   float* __restrict__ out) {
    int t = blockIdx.x * blockDim.x + threadIdx.x;   // cell-quad id
    const int nGroups = (BB * GG) / 4;               // 214272 = 837*256 exactly
    if (t >= nGroups) return;

    int cellBase = t * 4;
    int b = cellBase / GG;                           // G%4==0: quad never crosses batch
    int cellInB = cellBase - b * GG;

    int4 pids = ((const int4*)map)[t];
    const v4f* pf4 = (const v4f*)pf;                 // pf rows: 64 floats = 16 vec4
    const v4f* z4  = (const v4f*)(map + ZROW_INT_OFF);

    // Per-pillar base pointer: valid -> its pf row, invalid -> zero row.
    const v4f* p0 = (pids.x >= 0) ? (pf4 + pids.x * 16) : z4;
    const v4f* p1 = (pids.y >= 0) ? (pf4 + pids.y * 16) : z4;
    const v4f* p2 = (pids.z >= 0) ? (pf4 + pids.z * 16) : z4;
    const v4f* p3 = (pids.w >= 0) ? (pf4 + pids.w * 16) : z4;

    float* outBase = out + (size_t)(b * CC) * GG + cellInB;

    // 4 groups of 4 quads; within a group, 16 independent loads issue before
    // the dependent transpose+stores. __launch_bounds__ caps VGPR at 128 so
    // the compiler can pipeline across groups without spilling.
    #pragma unroll
    for (int g = 0; g < 4; ++g) {
        v4f r[4][4];
        #pragma unroll
        for (int j = 0; j < 4; ++j) {
            r[j][0] = p0[g * 4 + j];
            r[j][1] = p1[g * 4 + j];
            r[j][2] = p2[g * 4 + j];
            r[j][3] = p3[g * 4 + j];
        }
        #pragma unroll
        for (int j = 0; j < 4; ++j) {
            int c0 = (g * 4 + j) * 4;                // first of 4 channels
            v4f w0 = (v4f){r[j][0].x, r[j][1].x, r[j][2].x, r[j][3].x};
            v4f w1 = (v4f){r[j][0].y, r[j][1].y, r[j][2].y, r[j][3].y};
            v4f w2 = (v4f){r[j][0].z, r[j][1].z, r[j][2].z, r[j][3].z};
            v4f w3 = (v4f){r[j][0].w, r[j][1].w, r[j][2].w, r[j][3].w};

            *(v4f*)(outBase + (size_t)(c0 + 0) * GG) = w0;
            *(v4f*)(outBase + (size_t)(c0 + 1) * GG) = w1;
            *(v4f*)(outBase + (size_t)(c0 + 2) * GG) = w2;
            *(v4f*)(outBase + (size_t)(c0 + 3) * GG) = w3;
        }
    }
}

extern "C" void kernel_launch(void* const* d_in, const int* in_sizes, int n_in,
                              void* d_out, int out_size, void* d_ws, size_t ws_size,
                              hipStream_t stream) {
    const float* pf     = (const float*)d_in[0];     // [80000, 64] f32
    const int*   coords = (const int*)d_in[7];       // [80000, 4] i32 (b,z,y,x)
    float*       out    = (float*)d_out;             // [B, C, NY, NX] f32
    int*         map    = (int*)d_ws;                // [B*G] i32 + 64-float zero row

    const int n4 = (BB * GG) / 4;                    // 214272
    k_init_map<<<dim3((n4 + 255) / 256), dim3(256), 0, stream>>>(map);
    k_scatter_ids<<<dim3((PP + 255) / 256), dim3(256), 0, stream>>>(coords, map);

    const int nGroups = (BB * GG) / 4;               // 214272 = 837 * 256 exactly
    k_gather<<<dim3((nGroups + 255) / 256), dim3(256), 0, stream>>>(pf, map, out);
}